// Round 1
// baseline (518.727 us; speedup 1.0000x reference)
//
#include <hip/hip_runtime.h>
#include <hip/hip_bf16.h>

#define NN 100000
#define FIN 128
#define H8 64      // heads*hid = 8*8
#define NC 16

// ---------------- CSR build ----------------

__global__ void k_initdeg(int* __restrict__ deg, int n) {
    int i = blockIdx.x * 256 + threadIdx.x;
    if (i < n) deg[i] = 1;  // self-loop
}

__global__ void k_count(const int* __restrict__ dst, int* __restrict__ deg, int e) {
    int i = blockIdx.x * 256 + threadIdx.x;
    if (i < e) atomicAdd(&deg[dst[i]], 1);
}

__global__ __launch_bounds__(256) void k_scan1(const int* __restrict__ deg,
        int* __restrict__ rp, int* __restrict__ bsum, int n) {
    __shared__ int ts[256];
    int t = threadIdx.x;
    int base = blockIdx.x * 1024 + t * 4;
    int v0 = (base + 0 < n) ? deg[base + 0] : 0;
    int v1 = (base + 1 < n) ? deg[base + 1] : 0;
    int v2 = (base + 2 < n) ? deg[base + 2] : 0;
    int v3 = (base + 3 < n) ? deg[base + 3] : 0;
    int s = v0 + v1 + v2 + v3;
    ts[t] = s;
    __syncthreads();
    int run = s;
    for (int off = 1; off < 256; off <<= 1) {
        int y = (t >= off) ? ts[t - off] : 0;
        __syncthreads();
        run += y;
        ts[t] = run;
        __syncthreads();
    }
    int ex = run - s;
    if (base + 0 < n) { rp[base + 0] = ex; } ex += v0;
    if (base + 1 < n) { rp[base + 1] = ex; } ex += v1;
    if (base + 2 < n) { rp[base + 2] = ex; } ex += v2;
    if (base + 3 < n) { rp[base + 3] = ex; }
    if (t == 255) bsum[blockIdx.x] = run;
}

__global__ __launch_bounds__(256) void k_scan2(int* __restrict__ bsum, int nb) {
    __shared__ int ts[256];
    int t = threadIdx.x;
    int s = (t < nb) ? bsum[t] : 0;
    ts[t] = s;
    __syncthreads();
    int run = s;
    for (int off = 1; off < 256; off <<= 1) {
        int y = (t >= off) ? ts[t - off] : 0;
        __syncthreads();
        run += y;
        ts[t] = run;
        __syncthreads();
    }
    if (t < nb) bsum[t] = run - s;  // exclusive
}

__global__ void k_scan3(int* __restrict__ rp, const int* __restrict__ bsum,
                        int n, int total) {
    int i = blockIdx.x * 256 + threadIdx.x;
    if (i < n) rp[i] += bsum[i >> 10];
    if (i == 0) rp[n] = total;
}

__global__ void k_selfloop(const int* __restrict__ rp, int* __restrict__ wo,
                           int* __restrict__ col, int n) {
    int i = blockIdx.x * 256 + threadIdx.x;
    if (i < n) {
        int p = rp[i];
        col[p] = i;        // self-loop goes first
        wo[i] = p + 1;
    }
}

__global__ void k_scatter(const int* __restrict__ src, const int* __restrict__ dst,
                          int* __restrict__ wo, int* __restrict__ col, int e) {
    int i = blockIdx.x * 256 + threadIdx.x;
    if (i < e) {
        int d = dst[i];
        int p = atomicAdd(&wo[d], 1);
        col[p] = src[i];
    }
}

// ---------------- Layer 1 GEMM: h1 = x @ W1  (no bias) ----------------
// block = 256 threads, 16 nodes per block, W1 (128x64) fully in LDS.

__global__ __launch_bounds__(256) void k_gemm1(const float* __restrict__ x,
        const float* __restrict__ W, float* __restrict__ h1) {
    __shared__ float ws[FIN * H8];    // 32 KB
    __shared__ float xs[16][FIN];     // 8 KB
    int t = threadIdx.x;
    const float4* W4 = (const float4*)W;
    float4* ws4 = (float4*)ws;
    for (int j = t; j < FIN * H8 / 4; j += 256) ws4[j] = W4[j];
    int n0 = blockIdx.x * 16;
    const float4* x4 = (const float4*)(x + (long)n0 * FIN);
    float4* xs4 = (float4*)xs;
    for (int j = t; j < 16 * FIN / 4; j += 256) xs4[j] = x4[j];
    __syncthreads();
    int c = t & 63, s = t >> 6;   // s = wave id (0..3), each wave: 4 nodes
    float a0 = 0.f, a1 = 0.f, a2 = 0.f, a3 = 0.f;
#pragma unroll 8
    for (int k = 0; k < FIN; ++k) {
        float w = ws[k * H8 + c];
        a0 += xs[s * 4 + 0][k] * w;
        a1 += xs[s * 4 + 1][k] * w;
        a2 += xs[s * 4 + 2][k] * w;
        a3 += xs[s * 4 + 3][k] * w;
    }
    h1[(long)(n0 + s * 4 + 0) * H8 + c] = a0;
    h1[(long)(n0 + s * 4 + 1) * H8 + c] = a1;
    h1[(long)(n0 + s * 4 + 2) * H8 + c] = a2;
    h1[(long)(n0 + s * 4 + 3) * H8 + c] = a3;
}

// ---------------- Layer 1 attention coefficients ----------------

__device__ __forceinline__ float dot4(float4 a, float4 b) {
    return a.x * b.x + a.y * b.y + a.z * b.z + a.w * b.w;
}

__global__ void k_att1(const float* __restrict__ h1, const float* __restrict__ attS,
                       const float* __restrict__ attD, float* __restrict__ as1,
                       float* __restrict__ ad1, int n) {
    int t = blockIdx.x * 256 + threadIdx.x;
    if (t >= n * 8) return;
    int nd = t >> 3, h = t & 7;
    const float4* hp = (const float4*)(h1 + (long)nd * H8 + h * 8);
    float4 v0 = hp[0], v1 = hp[1];
    const float4* sp = (const float4*)(attS + h * 8);
    const float4* dp = (const float4*)(attD + h * 8);
    as1[t] = dot4(v0, sp[0]) + dot4(v1, sp[1]);
    ad1[t] = dot4(v0, dp[0]) + dot4(v1, dp[1]);
}

// ---------------- Layer 1 aggregation + bias + ReLU ----------------
// one 64-lane wave per node; lane = head*8 + channel

__global__ __launch_bounds__(256) void k_agg1(const int* __restrict__ rp,
        const int* __restrict__ col, const float* __restrict__ h1,
        const float* __restrict__ as1, const float* __restrict__ ad1,
        const float* __restrict__ b1, float* __restrict__ z1, int n) {
    int i = (blockIdx.x * 256 + threadIdx.x) >> 6;
    int lane = threadIdx.x & 63;
    if (i >= n) return;
    int h = lane >> 3;
    int beg = rp[i], end = rp[i + 1];
    float adi = ad1[i * 8 + h];
    float m = -1e30f, den = 0.f, num = 0.f;
    for (int k = beg; k < end; ++k) {
        int src = col[k];
        float sv = as1[src * 8 + h] + adi;
        float e = (sv > 0.f) ? sv : 0.2f * sv;
        float hv = h1[(long)src * H8 + lane];
        bool gt = e > m;
        float te = __expf(gt ? (m - e) : (e - m));
        float sc = gt ? te : 1.0f;
        float ex = gt ? 1.0f : te;
        den = den * sc + ex;
        num = num * sc + ex * hv;
        m = gt ? e : m;
    }
    float o = num / (den + 1e-16f) + b1[lane];
    z1[(long)i * H8 + lane] = fmaxf(o, 0.f);
}

// ---------------- Layer 2 GEMM + attention dots ----------------
// block = 256 threads = 16 nodes x 16 channels; W2 (64x16) in LDS

__global__ __launch_bounds__(256) void k_gemm2(const float* __restrict__ z1,
        const float* __restrict__ W2, const float* __restrict__ attS,
        const float* __restrict__ attD, float* __restrict__ h2,
        float* __restrict__ as2, float* __restrict__ ad2) {
    __shared__ float ws[H8 * NC];     // 4 KB
    __shared__ float zs[16][H8 + 1];  // padded
    int t = threadIdx.x;
    for (int j = t; j < H8 * NC; j += 256) ws[j] = W2[j];
    int n0 = blockIdx.x * 16;
    for (int j = t; j < 16 * H8; j += 256) {
        int r = j >> 6, k2 = j & 63;
        zs[r][k2] = z1[(long)(n0 + r) * H8 + k2];
    }
    __syncthreads();
    int c = t & 15, g = t >> 4;
    float acc = 0.f;
#pragma unroll 8
    for (int k = 0; k < H8; ++k) acc += zs[g][k] * ws[k * NC + c];
    h2[(long)(n0 + g) * NC + c] = acc;
    float vs = acc * attS[c], vd = acc * attD[c];
    for (int off = 1; off < 16; off <<= 1) {
        vs += __shfl_xor(vs, off, 64);
        vd += __shfl_xor(vd, off, 64);
    }
    if (c == 0) { as2[n0 + g] = vs; ad2[n0 + g] = vd; }
}

// ---------------- Layer 2 aggregation + bias + log_softmax ----------------
// one wave per node: 4 edge-slots x 16 channels

__global__ __launch_bounds__(256) void k_agg2(const int* __restrict__ rp,
        const int* __restrict__ col, const float* __restrict__ h2,
        const float* __restrict__ as2, const float* __restrict__ ad2,
        const float* __restrict__ b2, float* __restrict__ out, int n) {
    int i = (blockIdx.x * 256 + threadIdx.x) >> 6;
    int lane = threadIdx.x & 63;
    if (i >= n) return;
    int slot = lane >> 4, c = lane & 15;
    int beg = rp[i], end = rp[i + 1];
    float adi = ad2[i];
    float m = -1e30f, den = 0.f, num = 0.f;
    for (int k = beg + slot; k < end; k += 4) {
        int src = col[k];
        float sv = as2[src] + adi;
        float e = (sv > 0.f) ? sv : 0.2f * sv;
        float hv = h2[(long)src * NC + c];
        bool gt = e > m;
        float te = __expf(gt ? (m - e) : (e - m));
        float sc = gt ? te : 1.0f;
        float ex = gt ? 1.0f : te;
        den = den * sc + ex;
        num = num * sc + ex * hv;
        m = gt ? e : m;
    }
    // merge the 4 slots (butterfly over lane bits 4 and 5)
    for (int off = 16; off <= 32; off <<= 1) {
        float mo = __shfl_xor(m, off, 64);
        float dn = __shfl_xor(den, off, 64);
        float nm = __shfl_xor(num, off, 64);
        float mn = fmaxf(m, mo);
        float sa = __expf(m - mn);
        float sb = __expf(mo - mn);
        den = den * sa + dn * sb;
        num = num * sa + nm * sb;
        m = mn;
    }
    float o = num / (den + 1e-16f) + b2[c];
    // log_softmax across 16 channels (width-16 shuffle reduce)
    float mx = o;
    for (int off = 1; off < 16; off <<= 1) mx = fmaxf(mx, __shfl_xor(mx, off, 64));
    float ev = __expf(o - mx);
    float sm = ev;
    for (int off = 1; off < 16; off <<= 1) sm += __shfl_xor(sm, off, 64);
    float res = o - mx - __logf(sm);
    if (slot == 0) out[(long)i * NC + c] = res;
}

// ---------------- launcher ----------------

extern "C" void kernel_launch(void* const* d_in, const int* in_sizes, int n_in,
                              void* d_out, int out_size, void* d_ws, size_t ws_size,
                              hipStream_t stream) {
    const float* x     = (const float*)d_in[0];
    const int*   ei    = (const int*)d_in[1];
    const float* W1    = (const float*)d_in[2];
    const float* attS1 = (const float*)d_in[3];
    const float* attD1 = (const float*)d_in[4];
    const float* b1    = (const float*)d_in[5];
    const float* W2    = (const float*)d_in[6];
    const float* attS2 = (const float*)d_in[7];
    const float* attD2 = (const float*)d_in[8];
    const float* b2    = (const float*)d_in[9];
    float* out = (float*)d_out;

    const int N = NN;
    const int E = in_sizes[1] / 2;

    float* fws = (float*)d_ws;
    float* h1  = fws;                 // N*64
    float* z1  = h1 + (long)N * H8;   // N*64
    float* as1 = z1 + (long)N * H8;   // N*8
    float* ad1 = as1 + (long)N * 8;   // N*8
    float* h2  = ad1 + (long)N * 8;   // N*16
    float* as2 = h2 + (long)N * NC;   // N
    float* ad2 = as2 + N;             // N
    int* deg  = (int*)(ad2 + N);      // N
    int* rp   = deg + N;              // N+1
    int* wo   = rp + (N + 1);         // N
    int* col  = wo + N;               // E+N
    int* bsum = col + (E + N);        // <=256

    const int* srcp = ei;
    const int* dstp = ei + E;

    int nb = (N + 1023) / 1024;

    k_initdeg<<<(N + 255) / 256, 256, 0, stream>>>(deg, N);
    k_count<<<(E + 255) / 256, 256, 0, stream>>>(dstp, deg, E);
    k_scan1<<<nb, 256, 0, stream>>>(deg, rp, bsum, N);
    k_scan2<<<1, 256, 0, stream>>>(bsum, nb);
    k_scan3<<<(N + 255) / 256, 256, 0, stream>>>(rp, bsum, N, E + N);
    k_selfloop<<<(N + 255) / 256, 256, 0, stream>>>(rp, wo, col, N);
    k_scatter<<<(E + 255) / 256, 256, 0, stream>>>(srcp, dstp, wo, col, E);

    k_gemm1<<<N / 16, 256, 0, stream>>>(x, W1, h1);
    k_att1<<<(N * 8 + 255) / 256, 256, 0, stream>>>(h1, attS1, attD1, as1, ad1, N);
    k_agg1<<<(N + 3) / 4, 256, 0, stream>>>(rp, col, h1, as1, ad1, b1, z1, N);
    k_gemm2<<<N / 16, 256, 0, stream>>>(z1, W2, attS2, attD2, h2, as2, ad2);
    k_agg2<<<(N + 3) / 4, 256, 0, stream>>>(rp, col, h2, as2, ad2, b2, out, N);
}

// Round 2
// 394.905 us; speedup vs baseline: 1.3135x; 1.3135x over previous
//
#include <hip/hip_runtime.h>
#include <hip/hip_bf16.h>

#define NN 100000
#define FIN 128
#define H8 64      // heads*hid = 8*8
#define NC 16

typedef unsigned short ushort_t;

__device__ __forceinline__ float bu2f(ushort_t u) {
    unsigned v = ((unsigned)u) << 16;
    return __uint_as_float(v);
}
__device__ __forceinline__ ushort_t f2bu(float f) {
    __hip_bfloat16 h = __float2bfloat16(f);
    return *reinterpret_cast<ushort_t*>(&h);
}
__device__ __forceinline__ float dot4(float4 a, float4 b) {
    return a.x * b.x + a.y * b.y + a.z * b.z + a.w * b.w;
}
__device__ __forceinline__ void fma4(float4& a, float s, float4 w) {
    a.x += s * w.x; a.y += s * w.y; a.z += s * w.z; a.w += s * w.w;
}

// ---------------- CSR build ----------------

__global__ void k_initdeg(int* __restrict__ deg, int n) {
    int i = blockIdx.x * 256 + threadIdx.x;
    if (i < n) deg[i] = 1;  // self-loop
}

__global__ void k_count(const int* __restrict__ dst, int* __restrict__ deg, int e) {
    int i = blockIdx.x * 256 + threadIdx.x;
    if (i < e) atomicAdd(&deg[dst[i]], 1);
}

__global__ __launch_bounds__(256) void k_scan1(const int* __restrict__ deg,
        int* __restrict__ rp, int* __restrict__ bsum, int n) {
    __shared__ int ts[256];
    int t = threadIdx.x;
    int base = blockIdx.x * 1024 + t * 4;
    int v0 = (base + 0 < n) ? deg[base + 0] : 0;
    int v1 = (base + 1 < n) ? deg[base + 1] : 0;
    int v2 = (base + 2 < n) ? deg[base + 2] : 0;
    int v3 = (base + 3 < n) ? deg[base + 3] : 0;
    int s = v0 + v1 + v2 + v3;
    ts[t] = s;
    __syncthreads();
    int run = s;
    for (int off = 1; off < 256; off <<= 1) {
        int y = (t >= off) ? ts[t - off] : 0;
        __syncthreads();
        run += y;
        ts[t] = run;
        __syncthreads();
    }
    int ex = run - s;
    if (base + 0 < n) { rp[base + 0] = ex; } ex += v0;
    if (base + 1 < n) { rp[base + 1] = ex; } ex += v1;
    if (base + 2 < n) { rp[base + 2] = ex; } ex += v2;
    if (base + 3 < n) { rp[base + 3] = ex; }
    if (t == 255) bsum[blockIdx.x] = run;
}

__global__ __launch_bounds__(256) void k_scan2(int* __restrict__ bsum, int nb) {
    __shared__ int ts[256];
    int t = threadIdx.x;
    int s = (t < nb) ? bsum[t] : 0;
    ts[t] = s;
    __syncthreads();
    int run = s;
    for (int off = 1; off < 256; off <<= 1) {
        int y = (t >= off) ? ts[t - off] : 0;
        __syncthreads();
        run += y;
        ts[t] = run;
        __syncthreads();
    }
    if (t < nb) bsum[t] = run - s;  // exclusive
}

__global__ void k_scan3(int* __restrict__ rp, const int* __restrict__ bsum,
                        int n, int total) {
    int i = blockIdx.x * 256 + threadIdx.x;
    if (i < n) rp[i] += bsum[i >> 10];
    if (i == 0) rp[n] = total;
}

__global__ void k_selfloop(const int* __restrict__ rp, int* __restrict__ wo,
                           int* __restrict__ col, int n) {
    int i = blockIdx.x * 256 + threadIdx.x;
    if (i < n) {
        int p = rp[i];
        col[p] = i;        // self-loop goes first
        wo[i] = p + 1;
    }
}

__global__ void k_scatter(const int* __restrict__ src, const int* __restrict__ dst,
                          int* __restrict__ wo, int* __restrict__ col, int e) {
    int i = blockIdx.x * 256 + threadIdx.x;
    if (i < e) {
        int d = dst[i];
        int p = atomicAdd(&wo[d], 1);
        col[p] = src[i];
    }
}

// ---------------- Layer 1: h1 = x @ W1 (bf16 out) + fused att dots ----------------
// 256 thr = 4 waves; wave = 16 nodes x 64 ch; thread = 4 nodes x 4 ch.

__global__ __launch_bounds__(256) void k_gemm1(const float* __restrict__ x,
        const float* __restrict__ W, const float* __restrict__ attS,
        const float* __restrict__ attD, ushort_t* __restrict__ h1b,
        float* __restrict__ as1, float* __restrict__ ad1, int n) {
    __shared__ float ws[FIN * H8];    // 32 KB
    int t = threadIdx.x;
    const float4* W4 = (const float4*)W;
    float4* ws4 = (float4*)ws;
    for (int j = t; j < FIN * H8 / 4; j += 256) ws4[j] = W4[j];
    __syncthreads();

    int wv = t >> 6, lane = t & 63;
    int ng = lane >> 4, cg = lane & 15;
    int node0 = (blockIdx.x * 4 + wv) * 16 + ng * 4;

    int r0 = min(node0 + 0, n - 1), r1 = min(node0 + 1, n - 1);
    int r2 = min(node0 + 2, n - 1), r3 = min(node0 + 3, n - 1);
    const float* xp0 = x + (long)r0 * FIN;
    const float* xp1 = x + (long)r1 * FIN;
    const float* xp2 = x + (long)r2 * FIN;
    const float* xp3 = x + (long)r3 * FIN;

    float4 a0 = {0, 0, 0, 0}, a1 = {0, 0, 0, 0}, a2 = {0, 0, 0, 0}, a3 = {0, 0, 0, 0};
#pragma unroll 2
    for (int k = 0; k < FIN; k += 4) {
        float4 xa = *(const float4*)(xp0 + k);
        float4 xb = *(const float4*)(xp1 + k);
        float4 xc = *(const float4*)(xp2 + k);
        float4 xd = *(const float4*)(xp3 + k);
        float4 w0 = *(const float4*)(ws + (k + 0) * H8 + cg * 4);
        float4 w1 = *(const float4*)(ws + (k + 1) * H8 + cg * 4);
        float4 w2 = *(const float4*)(ws + (k + 2) * H8 + cg * 4);
        float4 w3 = *(const float4*)(ws + (k + 3) * H8 + cg * 4);
        fma4(a0, xa.x, w0); fma4(a0, xa.y, w1); fma4(a0, xa.z, w2); fma4(a0, xa.w, w3);
        fma4(a1, xb.x, w0); fma4(a1, xb.y, w1); fma4(a1, xb.z, w2); fma4(a1, xb.w, w3);
        fma4(a2, xc.x, w0); fma4(a2, xc.y, w1); fma4(a2, xc.z, w2); fma4(a2, xc.w, w3);
        fma4(a3, xd.x, w0); fma4(a3, xd.y, w1); fma4(a3, xd.z, w2); fma4(a3, xd.w, w3);
    }

    float4 sA = *(const float4*)(attS + cg * 4);
    float4 dA = *(const float4*)(attD + cg * 4);
    float4 av[4] = {a0, a1, a2, a3};
#pragma unroll
    for (int j = 0; j < 4; ++j) {
        int node = node0 + j;
        float4 a = av[j];
        float vs = dot4(a, sA);
        float vd = dot4(a, dA);
        vs += __shfl_xor(vs, 1, 64);   // sum channel-group pairs -> per-head dot
        vd += __shfl_xor(vd, 1, 64);
        if (node < n) {
            ushort4 q;
            q.x = f2bu(a.x); q.y = f2bu(a.y); q.z = f2bu(a.z); q.w = f2bu(a.w);
            *(ushort4*)(h1b + (long)node * H8 + cg * 4) = q;
            if ((lane & 1) == 0) {
                as1[node * 8 + (cg >> 1)] = vs;
                ad1[node * 8 + (cg >> 1)] = vd;
            }
        }
    }
}

// ---------------- Layer 1 aggregation + bias + ReLU ----------------
// one wave per node; lane = head*8 + channel; 8-wide masked edge pipeline

__global__ __launch_bounds__(256) void k_agg1(const int* __restrict__ rp,
        const int* __restrict__ col, const ushort_t* __restrict__ h1b,
        const float* __restrict__ as1, const float* __restrict__ ad1,
        const float* __restrict__ b1, float* __restrict__ z1, int n) {
    int i = (blockIdx.x * 256 + threadIdx.x) >> 6;
    int lane = threadIdx.x & 63;
    if (i >= n) return;
    int h = lane >> 3;
    int beg = rp[i], end = rp[i + 1];
    int deg = end - beg;
    float adi = ad1[i * 8 + h];
    float m = -1e30f, den = 0.f, num = 0.f;
    int rounds = (deg + 7) >> 3;
    for (int r = 0; r < rounds; ++r) {
        int kb = beg + r * 8;
        int s[8]; float sv[8]; ushort_t u[8]; float vm[8];
#pragma unroll
        for (int j = 0; j < 8; ++j) {
            int k = kb + j;
            bool v = k < end;
            vm[j] = v ? 1.f : 0.f;
            s[j] = col[v ? k : (end - 1)];
        }
#pragma unroll
        for (int j = 0; j < 8; ++j) {
            sv[j] = as1[s[j] * 8 + h];
            u[j] = h1b[(long)s[j] * H8 + lane];
        }
#pragma unroll
        for (int j = 0; j < 8; ++j) {
            float e0 = sv[j] + adi;
            float e = (e0 > 0.f) ? e0 : 0.2f * e0;
            float hv = bu2f(u[j]);
            bool gt = e > m;
            float te = __expf(gt ? (m - e) : (e - m));
            float sc = gt ? te : 1.0f;
            float ex = (gt ? 1.0f : te) * vm[j];
            den = den * sc + ex;
            num = num * sc + ex * hv;
            m = gt ? e : m;
        }
    }
    float o = num / (den + 1e-16f) + b1[lane];
    z1[(long)i * H8 + lane] = fmaxf(o, 0.f);
}

// ---------------- Layer 2 GEMM + attention dots (bf16 h2 out) ----------------

__global__ __launch_bounds__(256) void k_gemm2(const float* __restrict__ z1,
        const float* __restrict__ W2, const float* __restrict__ attS,
        const float* __restrict__ attD, ushort_t* __restrict__ h2b,
        float* __restrict__ as2, float* __restrict__ ad2) {
    __shared__ float ws[H8 * NC];     // 4 KB
    __shared__ float zs[16][H8 + 1];  // padded
    int t = threadIdx.x;
    for (int j = t; j < H8 * NC; j += 256) ws[j] = W2[j];
    int n0 = blockIdx.x * 16;
    for (int j = t; j < 16 * H8; j += 256) {
        int r = j >> 6, k2 = j & 63;
        zs[r][k2] = z1[(long)(n0 + r) * H8 + k2];
    }
    __syncthreads();
    int c = t & 15, g = t >> 4;
    float acc = 0.f;
#pragma unroll 8
    for (int k = 0; k < H8; ++k) acc += zs[g][k] * ws[k * NC + c];
    h2b[(long)(n0 + g) * NC + c] = f2bu(acc);
    float vs = acc * attS[c], vd = acc * attD[c];
    for (int off = 1; off < 16; off <<= 1) {
        vs += __shfl_xor(vs, off, 64);
        vd += __shfl_xor(vd, off, 64);
    }
    if (c == 0) { as2[n0 + g] = vs; ad2[n0 + g] = vd; }
}

// ---------------- Layer 2 aggregation + bias + log_softmax ----------------
// one wave per node: 4 edge-slots x 16 channels, 2-deep unroll (8 edges/round)

__global__ __launch_bounds__(256) void k_agg2(const int* __restrict__ rp,
        const int* __restrict__ col, const ushort_t* __restrict__ h2b,
        const float* __restrict__ as2, const float* __restrict__ ad2,
        const float* __restrict__ b2, float* __restrict__ out, int n) {
    int i = (blockIdx.x * 256 + threadIdx.x) >> 6;
    int lane = threadIdx.x & 63;
    if (i >= n) return;
    int slot = lane >> 4, c = lane & 15;
    int beg = rp[i], end = rp[i + 1];
    int deg = end - beg;
    float adi = ad2[i];
    float m = -1e30f, den = 0.f, num = 0.f;
    int rounds = (deg + 7) >> 3;
    for (int r = 0; r < rounds; ++r) {
        int kb = beg + r * 8;
        int k0 = kb + slot, k1 = kb + 4 + slot;
        bool v0 = k0 < end, v1 = k1 < end;
        int s0 = col[v0 ? k0 : (end - 1)];
        int s1 = col[v1 ? k1 : (end - 1)];
        float sv0 = as2[s0], sv1 = as2[s1];
        ushort_t u0 = h2b[(long)s0 * NC + c];
        ushort_t u1 = h2b[(long)s1 * NC + c];
        {
            float e0 = sv0 + adi;
            float e = (e0 > 0.f) ? e0 : 0.2f * e0;
            float hv = bu2f(u0);
            bool gt = e > m;
            float te = __expf(gt ? (m - e) : (e - m));
            float sc = gt ? te : 1.0f;
            float ex = (gt ? 1.0f : te) * (v0 ? 1.f : 0.f);
            den = den * sc + ex;
            num = num * sc + ex * hv;
            m = gt ? e : m;
        }
        {
            float e0 = sv1 + adi;
            float e = (e0 > 0.f) ? e0 : 0.2f * e0;
            float hv = bu2f(u1);
            bool gt = e > m;
            float te = __expf(gt ? (m - e) : (e - m));
            float sc = gt ? te : 1.0f;
            float ex = (gt ? 1.0f : te) * (v1 ? 1.f : 0.f);
            den = den * sc + ex;
            num = num * sc + ex * hv;
            m = gt ? e : m;
        }
    }
    // merge the 4 slots (butterfly over lane bits 4 and 5)
    for (int off = 16; off <= 32; off <<= 1) {
        float mo = __shfl_xor(m, off, 64);
        float dn = __shfl_xor(den, off, 64);
        float nm = __shfl_xor(num, off, 64);
        float mn = fmaxf(m, mo);
        float sa = __expf(m - mn);
        float sb = __expf(mo - mn);
        den = den * sa + dn * sb;
        num = num * sa + nm * sb;
        m = mn;
    }
    float o = num / (den + 1e-16f) + b2[c];
    // log_softmax across 16 channels
    float mx = o;
    for (int off = 1; off < 16; off <<= 1) mx = fmaxf(mx, __shfl_xor(mx, off, 64));
    float ev = __expf(o - mx);
    float sm = ev;
    for (int off = 1; off < 16; off <<= 1) sm += __shfl_xor(sm, off, 64);
    float res = o - mx - __logf(sm);
    if (slot == 0) out[(long)i * NC + c] = res;
}

// ---------------- launcher ----------------

extern "C" void kernel_launch(void* const* d_in, const int* in_sizes, int n_in,
                              void* d_out, int out_size, void* d_ws, size_t ws_size,
                              hipStream_t stream) {
    const float* x     = (const float*)d_in[0];
    const int*   ei    = (const int*)d_in[1];
    const float* W1    = (const float*)d_in[2];
    const float* attS1 = (const float*)d_in[3];
    const float* attD1 = (const float*)d_in[4];
    const float* b1    = (const float*)d_in[5];
    const float* W2    = (const float*)d_in[6];
    const float* attS2 = (const float*)d_in[7];
    const float* attD2 = (const float*)d_in[8];
    const float* b2    = (const float*)d_in[9];
    float* out = (float*)d_out;

    const int N = NN;
    const int E = in_sizes[1] / 2;

    float* fws = (float*)d_ws;
    float* z1  = fws;                       // N*64
    float* as1 = z1 + (size_t)N * H8;       // N*8
    float* ad1 = as1 + (size_t)N * 8;       // N*8
    float* as2 = ad1 + (size_t)N * 8;       // N
    float* ad2 = as2 + N;                   // N
    ushort_t* h1b = (ushort_t*)(ad2 + N);   // N*64 bf16
    ushort_t* h2b = h1b + (size_t)N * H8;   // N*16 bf16
    int* deg  = (int*)(h2b + (size_t)N * NC);
    int* rp   = deg + N;                    // N+1
    int* wo   = rp + (N + 1);               // N
    int* col  = wo + N;                     // E+N
    int* bsum = col + (E + N);              // <=256

    const int* srcp = ei;
    const int* dstp = ei + E;

    int nb = (N + 1023) / 1024;

    k_initdeg<<<(N + 255) / 256, 256, 0, stream>>>(deg, N);
    k_count<<<(E + 255) / 256, 256, 0, stream>>>(dstp, deg, E);
    k_scan1<<<nb, 256, 0, stream>>>(deg, rp, bsum, N);
    k_scan2<<<1, 256, 0, stream>>>(bsum, nb);
    k_scan3<<<(N + 255) / 256, 256, 0, stream>>>(rp, bsum, N, E + N);
    k_selfloop<<<(N + 255) / 256, 256, 0, stream>>>(rp, wo, col, N);
    k_scatter<<<(E + 255) / 256, 256, 0, stream>>>(srcp, dstp, wo, col, E);

    k_gemm1<<<(N + 63) / 64, 256, 0, stream>>>(x, W1, attS1, attD1, h1b, as1, ad1, N);
    k_agg1<<<(N + 3) / 4, 256, 0, stream>>>(rp, col, h1b, as1, ad1, b1, z1, N);
    k_gemm2<<<N / 16, 256, 0, stream>>>(z1, W2, attS2, attD2, h2b, as2, ad2);
    k_agg2<<<(N + 3) / 4, 256, 0, stream>>>(rp, col, h2b, as2, ad2, b2, out, N);
}

// Round 3
// 351.773 us; speedup vs baseline: 1.4746x; 1.1226x over previous
//
#include <hip/hip_runtime.h>
#include <hip/hip_bf16.h>

#define NN 100000
#define FIN 128
#define H8 64      // heads*hid = 8*8
#define NC 16
#define BKS 9      // bucket shift: 512 nodes/bucket
#define CHUNK 8192 // edges per binning block

typedef unsigned short ushort_t;
typedef unsigned long long u64_t;

__device__ __forceinline__ float bu2f(ushort_t u) {
    unsigned v = ((unsigned)u) << 16;
    return __uint_as_float(v);
}
__device__ __forceinline__ ushort_t f2bu(float f) {
    __hip_bfloat16 h = __float2bfloat16(f);
    return *reinterpret_cast<ushort_t*>(&h);
}
__device__ __forceinline__ float dot4(float4 a, float4 b) {
    return a.x * b.x + a.y * b.y + a.z * b.z + a.w * b.w;
}
__device__ __forceinline__ void fma4(float4& a, float s, float4 w) {
    a.x += s * w.x; a.y += s * w.y; a.z += s * w.z; a.w += s * w.w;
}

// ---------------- binned CSR build ----------------

// Pass A: per-block bucket histogram
__global__ __launch_bounds__(256) void k_binA(const int* __restrict__ dst,
        int* __restrict__ bh, int e, int nb) {
    __shared__ int hist[256];
    int t = threadIdx.x;
    hist[t] = 0;
    __syncthreads();
    int base = blockIdx.x * CHUNK;
    int endj = min(base + CHUNK, e);
    for (int k0 = base + t * 4; k0 < endj; k0 += 1024) {
        if (k0 + 3 < endj) {
            int4 d4 = *(const int4*)(dst + k0);
            atomicAdd(&hist[d4.x >> BKS], 1);
            atomicAdd(&hist[d4.y >> BKS], 1);
            atomicAdd(&hist[d4.z >> BKS], 1);
            atomicAdd(&hist[d4.w >> BKS], 1);
        } else {
            for (int k = k0; k < endj; ++k) atomicAdd(&hist[dst[k] >> BKS], 1);
        }
    }
    __syncthreads();
    if (t < nb) bh[blockIdx.x * nb + t] = hist[t];
}

// Pass B: bh[b][j] -> bucketStart[j] + prefix_{b'<b} bh[b'][j]   (single block)
__global__ __launch_bounds__(256) void k_binscan(int* __restrict__ bh,
        int nblk, int nb) {
    __shared__ int ts[256];
    int j = threadIdx.x;
    int tot = 0;
    if (j < nb) {
#pragma unroll 8
        for (int b = 0; b < nblk; ++b) {
            int v = bh[b * nb + j];
            bh[b * nb + j] = tot;
            tot += v;
        }
    }
    ts[j] = tot;
    __syncthreads();
    int run = ts[j];
    for (int off = 1; off < 256; off <<= 1) {
        int y = (j >= off) ? ts[j - off] : 0;
        __syncthreads();
        run += y;
        ts[j] = run;
        __syncthreads();
    }
    int start = run - tot;   // exclusive over buckets
    if (j < nb) {
#pragma unroll 8
        for (int b = 0; b < nblk; ++b) bh[b * nb + j] += start;
    }
}

// Pass C: scatter packed (dst,src) into bucket-grouped array
__global__ __launch_bounds__(256) void k_binC(const int* __restrict__ src,
        const int* __restrict__ dst, const int* __restrict__ bh,
        u64_t* __restrict__ binned, int e, int nb) {
    __shared__ int off[256];
    int t = threadIdx.x;
    if (t < nb) off[t] = bh[blockIdx.x * nb + t];
    __syncthreads();
    int base = blockIdx.x * CHUNK;
    int endj = min(base + CHUNK, e);
    for (int k0 = base + t * 4; k0 < endj; k0 += 1024) {
        if (k0 + 3 < endj) {
            int4 d4 = *(const int4*)(dst + k0);
            int4 s4 = *(const int4*)(src + k0);
            int p0 = atomicAdd(&off[d4.x >> BKS], 1);
            binned[p0] = ((u64_t)(unsigned)d4.x << 32) | (unsigned)s4.x;
            int p1 = atomicAdd(&off[d4.y >> BKS], 1);
            binned[p1] = ((u64_t)(unsigned)d4.y << 32) | (unsigned)s4.y;
            int p2 = atomicAdd(&off[d4.z >> BKS], 1);
            binned[p2] = ((u64_t)(unsigned)d4.z << 32) | (unsigned)s4.z;
            int p3 = atomicAdd(&off[d4.w >> BKS], 1);
            binned[p3] = ((u64_t)(unsigned)d4.w << 32) | (unsigned)s4.w;
        } else {
            for (int k = k0; k < endj; ++k) {
                int d = dst[k], s = src[k];
                int p = atomicAdd(&off[d >> BKS], 1);
                binned[p] = ((u64_t)(unsigned)d << 32) | (unsigned)s;
            }
        }
    }
}

// degree count from bucket-grouped edges (L2-local atomics)
__global__ void k_count2(const u64_t* __restrict__ binned, int* __restrict__ deg, int e) {
    int i = blockIdx.x * 256 + threadIdx.x;
    if (i < e) atomicAdd(&deg[(int)(binned[i] >> 32)], 1);
}

__global__ __launch_bounds__(256) void k_scan1(const int* __restrict__ deg,
        int* __restrict__ rp, int* __restrict__ bsum, int n) {
    __shared__ int ts[256];
    int t = threadIdx.x;
    int base = blockIdx.x * 1024 + t * 4;
    // +1 per node: self-loop
    int v0 = (base + 0 < n) ? deg[base + 0] + 1 : 0;
    int v1 = (base + 1 < n) ? deg[base + 1] + 1 : 0;
    int v2 = (base + 2 < n) ? deg[base + 2] + 1 : 0;
    int v3 = (base + 3 < n) ? deg[base + 3] + 1 : 0;
    int s = v0 + v1 + v2 + v3;
    ts[t] = s;
    __syncthreads();
    int run = s;
    for (int off = 1; off < 256; off <<= 1) {
        int y = (t >= off) ? ts[t - off] : 0;
        __syncthreads();
        run += y;
        ts[t] = run;
        __syncthreads();
    }
    int ex = run - s;
    if (base + 0 < n) { rp[base + 0] = ex; } ex += v0;
    if (base + 1 < n) { rp[base + 1] = ex; } ex += v1;
    if (base + 2 < n) { rp[base + 2] = ex; } ex += v2;
    if (base + 3 < n) { rp[base + 3] = ex; }
    if (t == 255) bsum[blockIdx.x] = run;
}

__global__ __launch_bounds__(256) void k_scan2(int* __restrict__ bsum, int nb) {
    __shared__ int ts[256];
    int t = threadIdx.x;
    int s = (t < nb) ? bsum[t] : 0;
    ts[t] = s;
    __syncthreads();
    int run = s;
    for (int off = 1; off < 256; off <<= 1) {
        int y = (t >= off) ? ts[t - off] : 0;
        __syncthreads();
        run += y;
        ts[t] = run;
        __syncthreads();
    }
    if (t < nb) bsum[t] = run - s;  // exclusive
}

__global__ void k_scan3(int* __restrict__ rp, const int* __restrict__ bsum,
                        int n, int total) {
    int i = blockIdx.x * 256 + threadIdx.x;
    if (i < n) rp[i] += bsum[i >> 10];
    if (i == 0) rp[n] = total;
}

__global__ void k_selfloop(const int* __restrict__ rp, int* __restrict__ wo,
                           int* __restrict__ col, int n) {
    int i = blockIdx.x * 256 + threadIdx.x;
    if (i < n) {
        int p = rp[i];
        col[p] = i;        // self-loop goes first
        wo[i] = p + 1;
    }
}

// final CSR scatter from bucket-grouped edges (L2-hot wo/col windows)
__global__ void k_binD(const u64_t* __restrict__ binned, int* __restrict__ wo,
                       int* __restrict__ col, int e) {
    int i = blockIdx.x * 256 + threadIdx.x;
    if (i < e) {
        u64_t pk = binned[i];
        int d = (int)(pk >> 32);
        int s = (int)(pk & 0xffffffffu);
        int p = atomicAdd(&wo[d], 1);
        col[p] = s;
    }
}

// ---------------- Layer 1: h1 = x @ W1 (bf16 out) + fused att dots ----------------
// 256 thr = 4 waves; wave = 16 nodes x 64 ch; thread = 4 nodes x 4 ch.

__global__ __launch_bounds__(256) void k_gemm1(const float* __restrict__ x,
        const float* __restrict__ W, const float* __restrict__ attS,
        const float* __restrict__ attD, ushort_t* __restrict__ h1b,
        float* __restrict__ as1, float* __restrict__ ad1, int n) {
    __shared__ float ws[FIN * H8];    // 32 KB
    int t = threadIdx.x;
    const float4* W4 = (const float4*)W;
    float4* ws4 = (float4*)ws;
    for (int j = t; j < FIN * H8 / 4; j += 256) ws4[j] = W4[j];
    __syncthreads();

    int wv = t >> 6, lane = t & 63;
    int ng = lane >> 4, cg = lane & 15;
    int node0 = (blockIdx.x * 4 + wv) * 16 + ng * 4;

    int r0 = min(node0 + 0, n - 1), r1 = min(node0 + 1, n - 1);
    int r2 = min(node0 + 2, n - 1), r3 = min(node0 + 3, n - 1);
    const float* xp0 = x + (long)r0 * FIN;
    const float* xp1 = x + (long)r1 * FIN;
    const float* xp2 = x + (long)r2 * FIN;
    const float* xp3 = x + (long)r3 * FIN;

    float4 a0 = {0, 0, 0, 0}, a1 = {0, 0, 0, 0}, a2 = {0, 0, 0, 0}, a3 = {0, 0, 0, 0};
#pragma unroll 2
    for (int k = 0; k < FIN; k += 4) {
        float4 xa = *(const float4*)(xp0 + k);
        float4 xb = *(const float4*)(xp1 + k);
        float4 xc = *(const float4*)(xp2 + k);
        float4 xd = *(const float4*)(xp3 + k);
        float4 w0 = *(const float4*)(ws + (k + 0) * H8 + cg * 4);
        float4 w1 = *(const float4*)(ws + (k + 1) * H8 + cg * 4);
        float4 w2 = *(const float4*)(ws + (k + 2) * H8 + cg * 4);
        float4 w3 = *(const float4*)(ws + (k + 3) * H8 + cg * 4);
        fma4(a0, xa.x, w0); fma4(a0, xa.y, w1); fma4(a0, xa.z, w2); fma4(a0, xa.w, w3);
        fma4(a1, xb.x, w0); fma4(a1, xb.y, w1); fma4(a1, xb.z, w2); fma4(a1, xb.w, w3);
        fma4(a2, xc.x, w0); fma4(a2, xc.y, w1); fma4(a2, xc.z, w2); fma4(a2, xc.w, w3);
        fma4(a3, xd.x, w0); fma4(a3, xd.y, w1); fma4(a3, xd.z, w2); fma4(a3, xd.w, w3);
    }

    float4 sA = *(const float4*)(attS + cg * 4);
    float4 dA = *(const float4*)(attD + cg * 4);
    float4 av[4] = {a0, a1, a2, a3};
#pragma unroll
    for (int j = 0; j < 4; ++j) {
        int node = node0 + j;
        float4 a = av[j];
        float vs = dot4(a, sA);
        float vd = dot4(a, dA);
        vs += __shfl_xor(vs, 1, 64);   // sum channel-group pairs -> per-head dot
        vd += __shfl_xor(vd, 1, 64);
        if (node < n) {
            ushort4 q;
            q.x = f2bu(a.x); q.y = f2bu(a.y); q.z = f2bu(a.z); q.w = f2bu(a.w);
            *(ushort4*)(h1b + (long)node * H8 + cg * 4) = q;
            if ((lane & 1) == 0) {
                as1[node * 8 + (cg >> 1)] = vs;
                ad1[node * 8 + (cg >> 1)] = vd;
            }
        }
    }
}

// ---------------- Layer 1 aggregation + bias + ReLU ----------------

__global__ __launch_bounds__(256) void k_agg1(const int* __restrict__ rp,
        const int* __restrict__ col, const ushort_t* __restrict__ h1b,
        const float* __restrict__ as1, const float* __restrict__ ad1,
        const float* __restrict__ b1, float* __restrict__ z1, int n) {
    int i = (blockIdx.x * 256 + threadIdx.x) >> 6;
    int lane = threadIdx.x & 63;
    if (i >= n) return;
    int h = lane >> 3;
    int beg = rp[i], end = rp[i + 1];
    int deg = end - beg;
    float adi = ad1[i * 8 + h];
    float m = -1e30f, den = 0.f, num = 0.f;
    int rounds = (deg + 7) >> 3;
    for (int r = 0; r < rounds; ++r) {
        int kb = beg + r * 8;
        int s[8]; float sv[8]; ushort_t u[8]; float vm[8];
#pragma unroll
        for (int j = 0; j < 8; ++j) {
            int k = kb + j;
            bool v = k < end;
            vm[j] = v ? 1.f : 0.f;
            s[j] = col[v ? k : (end - 1)];
        }
#pragma unroll
        for (int j = 0; j < 8; ++j) {
            sv[j] = as1[s[j] * 8 + h];
            u[j] = h1b[(long)s[j] * H8 + lane];
        }
#pragma unroll
        for (int j = 0; j < 8; ++j) {
            float e0 = sv[j] + adi;
            float e = (e0 > 0.f) ? e0 : 0.2f * e0;
            float hv = bu2f(u[j]);
            bool gt = e > m;
            float te = __expf(gt ? (m - e) : (e - m));
            float sc = gt ? te : 1.0f;
            float ex = (gt ? 1.0f : te) * vm[j];
            den = den * sc + ex;
            num = num * sc + ex * hv;
            m = gt ? e : m;
        }
    }
    float o = num / (den + 1e-16f) + b1[lane];
    z1[(long)i * H8 + lane] = fmaxf(o, 0.f);
}

// ---------------- Layer 2 GEMM + attention dots (bf16 h2 out) ----------------

__global__ __launch_bounds__(256) void k_gemm2(const float* __restrict__ z1,
        const float* __restrict__ W2, const float* __restrict__ attS,
        const float* __restrict__ attD, ushort_t* __restrict__ h2b,
        float* __restrict__ as2, float* __restrict__ ad2) {
    __shared__ float ws[H8 * NC];     // 4 KB
    __shared__ float zs[16][H8 + 1];  // padded
    int t = threadIdx.x;
    for (int j = t; j < H8 * NC; j += 256) ws[j] = W2[j];
    int n0 = blockIdx.x * 16;
    for (int j = t; j < 16 * H8; j += 256) {
        int r = j >> 6, k2 = j & 63;
        zs[r][k2] = z1[(long)(n0 + r) * H8 + k2];
    }
    __syncthreads();
    int c = t & 15, g = t >> 4;
    float acc = 0.f;
#pragma unroll 8
    for (int k = 0; k < H8; ++k) acc += zs[g][k] * ws[k * NC + c];
    h2b[(long)(n0 + g) * NC + c] = f2bu(acc);
    float vs = acc * attS[c], vd = acc * attD[c];
    for (int off = 1; off < 16; off <<= 1) {
        vs += __shfl_xor(vs, off, 64);
        vd += __shfl_xor(vd, off, 64);
    }
    if (c == 0) { as2[n0 + g] = vs; ad2[n0 + g] = vd; }
}

// ---------------- Layer 2 aggregation + bias + log_softmax ----------------

__global__ __launch_bounds__(256) void k_agg2(const int* __restrict__ rp,
        const int* __restrict__ col, const ushort_t* __restrict__ h2b,
        const float* __restrict__ as2, const float* __restrict__ ad2,
        const float* __restrict__ b2, float* __restrict__ out, int n) {
    int i = (blockIdx.x * 256 + threadIdx.x) >> 6;
    int lane = threadIdx.x & 63;
    if (i >= n) return;
    int slot = lane >> 4, c = lane & 15;
    int beg = rp[i], end = rp[i + 1];
    int deg = end - beg;
    float adi = ad2[i];
    float m = -1e30f, den = 0.f, num = 0.f;
    int rounds = (deg + 7) >> 3;
    for (int r = 0; r < rounds; ++r) {
        int kb = beg + r * 8;
        int k0 = kb + slot, k1 = kb + 4 + slot;
        bool v0 = k0 < end, v1 = k1 < end;
        int s0 = col[v0 ? k0 : (end - 1)];
        int s1 = col[v1 ? k1 : (end - 1)];
        float sv0 = as2[s0], sv1 = as2[s1];
        ushort_t u0 = h2b[(long)s0 * NC + c];
        ushort_t u1 = h2b[(long)s1 * NC + c];
        {
            float e0 = sv0 + adi;
            float e = (e0 > 0.f) ? e0 : 0.2f * e0;
            float hv = bu2f(u0);
            bool gt = e > m;
            float te = __expf(gt ? (m - e) : (e - m));
            float sc = gt ? te : 1.0f;
            float ex = (gt ? 1.0f : te) * (v0 ? 1.f : 0.f);
            den = den * sc + ex;
            num = num * sc + ex * hv;
            m = gt ? e : m;
        }
        {
            float e0 = sv1 + adi;
            float e = (e0 > 0.f) ? e0 : 0.2f * e0;
            float hv = bu2f(u1);
            bool gt = e > m;
            float te = __expf(gt ? (m - e) : (e - m));
            float sc = gt ? te : 1.0f;
            float ex = (gt ? 1.0f : te) * (v1 ? 1.f : 0.f);
            den = den * sc + ex;
            num = num * sc + ex * hv;
            m = gt ? e : m;
        }
    }
    for (int off = 16; off <= 32; off <<= 1) {
        float mo = __shfl_xor(m, off, 64);
        float dn = __shfl_xor(den, off, 64);
        float nm = __shfl_xor(num, off, 64);
        float mn = fmaxf(m, mo);
        float sa = __expf(m - mn);
        float sb = __expf(mo - mn);
        den = den * sa + dn * sb;
        num = num * sa + nm * sb;
        m = mn;
    }
    float o = num / (den + 1e-16f) + b2[c];
    float mx = o;
    for (int off = 1; off < 16; off <<= 1) mx = fmaxf(mx, __shfl_xor(mx, off, 64));
    float ev = __expf(o - mx);
    float sm = ev;
    for (int off = 1; off < 16; off <<= 1) sm += __shfl_xor(sm, off, 64);
    float res = o - mx - __logf(sm);
    if (slot == 0) out[(long)i * NC + c] = res;
}

// ---------------- launcher ----------------

extern "C" void kernel_launch(void* const* d_in, const int* in_sizes, int n_in,
                              void* d_out, int out_size, void* d_ws, size_t ws_size,
                              hipStream_t stream) {
    const float* x     = (const float*)d_in[0];
    const int*   ei    = (const int*)d_in[1];
    const float* W1    = (const float*)d_in[2];
    const float* attS1 = (const float*)d_in[3];
    const float* attD1 = (const float*)d_in[4];
    const float* b1    = (const float*)d_in[5];
    const float* W2    = (const float*)d_in[6];
    const float* attS2 = (const float*)d_in[7];
    const float* attD2 = (const float*)d_in[8];
    const float* b2    = (const float*)d_in[9];
    float* out = (float*)d_out;

    const int N = NN;
    const int E = in_sizes[1] / 2;
    const int NB = (N + (1 << BKS) - 1) >> BKS;      // 196 buckets
    const int NBLK = (E + CHUNK - 1) / CHUNK;        // binning blocks

    float* fws = (float*)d_ws;
    float* z1  = fws;                       // N*64  (aliased by binned before agg1)
    float* as1 = z1 + (size_t)N * H8;       // N*8
    float* ad1 = as1 + (size_t)N * 8;       // N*8
    float* as2 = ad1 + (size_t)N * 8;       // N
    float* ad2 = as2 + N;                   // N
    ushort_t* h1b = (ushort_t*)(ad2 + N);   // N*64 bf16
    ushort_t* h2b = h1b + (size_t)N * H8;   // N*16 bf16
    int* deg  = (int*)(h2b + (size_t)N * NC);
    int* rp   = deg + N;                    // N+1
    int* wo   = rp + (N + 1);               // N
    int* col  = wo + N;                     // E+N
    int* bh   = col + (E + N);              // NBLK*NB
    int* bsum = bh + (size_t)NBLK * NB;     // <=256
    u64_t* binned = (u64_t*)z1;             // E * 8B  (z1 is 25.6MB >= 12.8MB)

    const int* srcp = ei;
    const int* dstp = ei + E;

    int nb1024 = (N + 1023) / 1024;

    hipMemsetAsync(deg, 0, (size_t)N * 4, stream);
    k_binA<<<NBLK, 256, 0, stream>>>(dstp, bh, E, NB);
    k_binscan<<<1, 256, 0, stream>>>(bh, NBLK, NB);
    k_binC<<<NBLK, 256, 0, stream>>>(srcp, dstp, bh, binned, E, NB);
    k_count2<<<(E + 255) / 256, 256, 0, stream>>>(binned, deg, E);
    k_scan1<<<nb1024, 256, 0, stream>>>(deg, rp, bsum, N);
    k_scan2<<<1, 256, 0, stream>>>(bsum, nb1024);
    k_scan3<<<(N + 255) / 256, 256, 0, stream>>>(rp, bsum, N, E + N);
    k_selfloop<<<(N + 255) / 256, 256, 0, stream>>>(rp, wo, col, N);
    k_binD<<<(E + 255) / 256, 256, 0, stream>>>(binned, wo, col, E);

    k_gemm1<<<(N + 63) / 64, 256, 0, stream>>>(x, W1, attS1, attD1, h1b, as1, ad1, N);
    k_agg1<<<(N + 3) / 4, 256, 0, stream>>>(rp, col, h1b, as1, ad1, b1, z1, N);
    k_gemm2<<<N / 16, 256, 0, stream>>>(z1, W2, attS2, attD2, h2b, as2, ad2);
    k_agg2<<<(N + 3) / 4, 256, 0, stream>>>(rp, col, h2b, as2, ad2, b2, out, N);
}

// Round 4
// 329.585 us; speedup vs baseline: 1.5739x; 1.0673x over previous
//
#include <hip/hip_runtime.h>
#include <hip/hip_bf16.h>

#define NN 100000
#define FIN 128
#define H8 64      // heads*hid = 8*8
#define NC 16
#define BKS 9      // bucket shift: 512 nodes/bucket
#define CHUNK 8192 // edges per binning block

typedef unsigned short ushort_t;
typedef unsigned long long u64_t;

__device__ __forceinline__ float bu2f(ushort_t u) {
    unsigned v = ((unsigned)u) << 16;
    return __uint_as_float(v);
}
__device__ __forceinline__ ushort_t f2bu(float f) {
    __hip_bfloat16 h = __float2bfloat16(f);
    return *reinterpret_cast<ushort_t*>(&h);
}
__device__ __forceinline__ float dot4(float4 a, float4 b) {
    return a.x * b.x + a.y * b.y + a.z * b.z + a.w * b.w;
}
__device__ __forceinline__ void fma4(float4& a, float s, float4 w) {
    a.x += s * w.x; a.y += s * w.y; a.z += s * w.z; a.w += s * w.w;
}

// ---------------- binned CSR build ----------------

__global__ __launch_bounds__(256) void k_binA(const int* __restrict__ dst,
        int* __restrict__ bh, int e, int nb) {
    __shared__ int hist[256];
    int t = threadIdx.x;
    hist[t] = 0;
    __syncthreads();
    int base = blockIdx.x * CHUNK;
    int endj = min(base + CHUNK, e);
    for (int k0 = base + t * 4; k0 < endj; k0 += 1024) {
        if (k0 + 3 < endj) {
            int4 d4 = *(const int4*)(dst + k0);
            atomicAdd(&hist[d4.x >> BKS], 1);
            atomicAdd(&hist[d4.y >> BKS], 1);
            atomicAdd(&hist[d4.z >> BKS], 1);
            atomicAdd(&hist[d4.w >> BKS], 1);
        } else {
            for (int k = k0; k < endj; ++k) atomicAdd(&hist[dst[k] >> BKS], 1);
        }
    }
    __syncthreads();
    if (t < nb) bh[blockIdx.x * nb + t] = hist[t];
}

__global__ __launch_bounds__(256) void k_binscan(int* __restrict__ bh,
        int nblk, int nb) {
    __shared__ int ts[256];
    int j = threadIdx.x;
    int tot = 0;
    if (j < nb) {
#pragma unroll 8
        for (int b = 0; b < nblk; ++b) {
            int v = bh[b * nb + j];
            bh[b * nb + j] = tot;
            tot += v;
        }
    }
    ts[j] = tot;
    __syncthreads();
    int run = ts[j];
    for (int off = 1; off < 256; off <<= 1) {
        int y = (j >= off) ? ts[j - off] : 0;
        __syncthreads();
        run += y;
        ts[j] = run;
        __syncthreads();
    }
    int start = run - tot;   // exclusive over buckets
    if (j < nb) {
#pragma unroll 8
        for (int b = 0; b < nblk; ++b) bh[b * nb + j] += start;
    }
}

__global__ __launch_bounds__(256) void k_binC(const int* __restrict__ src,
        const int* __restrict__ dst, const int* __restrict__ bh,
        u64_t* __restrict__ binned, int e, int nb) {
    __shared__ int off[256];
    int t = threadIdx.x;
    if (t < nb) off[t] = bh[blockIdx.x * nb + t];
    __syncthreads();
    int base = blockIdx.x * CHUNK;
    int endj = min(base + CHUNK, e);
    for (int k0 = base + t * 4; k0 < endj; k0 += 1024) {
        if (k0 + 3 < endj) {
            int4 d4 = *(const int4*)(dst + k0);
            int4 s4 = *(const int4*)(src + k0);
            int p0 = atomicAdd(&off[d4.x >> BKS], 1);
            binned[p0] = ((u64_t)(unsigned)d4.x << 32) | (unsigned)s4.x;
            int p1 = atomicAdd(&off[d4.y >> BKS], 1);
            binned[p1] = ((u64_t)(unsigned)d4.y << 32) | (unsigned)s4.y;
            int p2 = atomicAdd(&off[d4.z >> BKS], 1);
            binned[p2] = ((u64_t)(unsigned)d4.z << 32) | (unsigned)s4.z;
            int p3 = atomicAdd(&off[d4.w >> BKS], 1);
            binned[p3] = ((u64_t)(unsigned)d4.w << 32) | (unsigned)s4.w;
        } else {
            for (int k = k0; k < endj; ++k) {
                int d = dst[k], s = src[k];
                int p = atomicAdd(&off[d >> BKS], 1);
                binned[p] = ((u64_t)(unsigned)d << 32) | (unsigned)s;
            }
        }
    }
}

__global__ void k_count2(const u64_t* __restrict__ binned, int* __restrict__ deg, int e) {
    int i = blockIdx.x * 256 + threadIdx.x;
    if (i < e) atomicAdd(&deg[(int)(binned[i] >> 32)], 1);
}

__global__ __launch_bounds__(256) void k_scan1(const int* __restrict__ deg,
        int* __restrict__ rp, int* __restrict__ bsum, int n) {
    __shared__ int ts[256];
    int t = threadIdx.x;
    int base = blockIdx.x * 1024 + t * 4;
    int v0 = (base + 0 < n) ? deg[base + 0] + 1 : 0;
    int v1 = (base + 1 < n) ? deg[base + 1] + 1 : 0;
    int v2 = (base + 2 < n) ? deg[base + 2] + 1 : 0;
    int v3 = (base + 3 < n) ? deg[base + 3] + 1 : 0;
    int s = v0 + v1 + v2 + v3;
    ts[t] = s;
    __syncthreads();
    int run = s;
    for (int off = 1; off < 256; off <<= 1) {
        int y = (t >= off) ? ts[t - off] : 0;
        __syncthreads();
        run += y;
        ts[t] = run;
        __syncthreads();
    }
    int ex = run - s;
    if (base + 0 < n) { rp[base + 0] = ex; } ex += v0;
    if (base + 1 < n) { rp[base + 1] = ex; } ex += v1;
    if (base + 2 < n) { rp[base + 2] = ex; } ex += v2;
    if (base + 3 < n) { rp[base + 3] = ex; }
    if (t == 255) bsum[blockIdx.x] = run;
}

__global__ __launch_bounds__(256) void k_scan2(int* __restrict__ bsum, int nb) {
    __shared__ int ts[256];
    int t = threadIdx.x;
    int s = (t < nb) ? bsum[t] : 0;
    ts[t] = s;
    __syncthreads();
    int run = s;
    for (int off = 1; off < 256; off <<= 1) {
        int y = (t >= off) ? ts[t - off] : 0;
        __syncthreads();
        run += y;
        ts[t] = run;
        __syncthreads();
    }
    if (t < nb) bsum[t] = run - s;  // exclusive
}

__global__ void k_scan3(int* __restrict__ rp, const int* __restrict__ bsum,
                        int n, int total) {
    int i = blockIdx.x * 256 + threadIdx.x;
    if (i < n) rp[i] += bsum[i >> 10];
    if (i == 0) rp[n] = total;
}

__global__ void k_selfloop(const int* __restrict__ rp, int* __restrict__ wo,
                           int* __restrict__ col, int n) {
    int i = blockIdx.x * 256 + threadIdx.x;
    if (i < n) {
        int p = rp[i];
        col[p] = i;        // self-loop goes first
        wo[i] = p + 1;
    }
}

__global__ void k_binD(const u64_t* __restrict__ binned, int* __restrict__ wo,
                       int* __restrict__ col, int e) {
    int i = blockIdx.x * 256 + threadIdx.x;
    if (i < e) {
        u64_t pk = binned[i];
        int d = (int)(pk >> 32);
        int s = (int)(pk & 0xffffffffu);
        int p = atomicAdd(&wo[d], 1);
        col[p] = s;
    }
}

// ---------------- Layer 1: h1 = x @ W1 (bf16 out) + fused att dots ----------------

__global__ __launch_bounds__(256) void k_gemm1(const float* __restrict__ x,
        const float* __restrict__ W, const float* __restrict__ attS,
        const float* __restrict__ attD, ushort_t* __restrict__ h1b,
        float* __restrict__ as1, float* __restrict__ ad1, int n) {
    __shared__ float ws[FIN * H8];    // 32 KB
    int t = threadIdx.x;
    const float4* W4 = (const float4*)W;
    float4* ws4 = (float4*)ws;
    for (int j = t; j < FIN * H8 / 4; j += 256) ws4[j] = W4[j];
    __syncthreads();

    int wv = t >> 6, lane = t & 63;
    int ng = lane >> 4, cg = lane & 15;
    int node0 = (blockIdx.x * 4 + wv) * 16 + ng * 4;

    int r0 = min(node0 + 0, n - 1), r1 = min(node0 + 1, n - 1);
    int r2 = min(node0 + 2, n - 1), r3 = min(node0 + 3, n - 1);
    const float* xp0 = x + (long)r0 * FIN;
    const float* xp1 = x + (long)r1 * FIN;
    const float* xp2 = x + (long)r2 * FIN;
    const float* xp3 = x + (long)r3 * FIN;

    float4 a0 = {0, 0, 0, 0}, a1 = {0, 0, 0, 0}, a2 = {0, 0, 0, 0}, a3 = {0, 0, 0, 0};
#pragma unroll 2
    for (int k = 0; k < FIN; k += 4) {
        float4 xa = *(const float4*)(xp0 + k);
        float4 xb = *(const float4*)(xp1 + k);
        float4 xc = *(const float4*)(xp2 + k);
        float4 xd = *(const float4*)(xp3 + k);
        float4 w0 = *(const float4*)(ws + (k + 0) * H8 + cg * 4);
        float4 w1 = *(const float4*)(ws + (k + 1) * H8 + cg * 4);
        float4 w2 = *(const float4*)(ws + (k + 2) * H8 + cg * 4);
        float4 w3 = *(const float4*)(ws + (k + 3) * H8 + cg * 4);
        fma4(a0, xa.x, w0); fma4(a0, xa.y, w1); fma4(a0, xa.z, w2); fma4(a0, xa.w, w3);
        fma4(a1, xb.x, w0); fma4(a1, xb.y, w1); fma4(a1, xb.z, w2); fma4(a1, xb.w, w3);
        fma4(a2, xc.x, w0); fma4(a2, xc.y, w1); fma4(a2, xc.z, w2); fma4(a2, xc.w, w3);
        fma4(a3, xd.x, w0); fma4(a3, xd.y, w1); fma4(a3, xd.z, w2); fma4(a3, xd.w, w3);
    }

    float4 sA = *(const float4*)(attS + cg * 4);
    float4 dA = *(const float4*)(attD + cg * 4);
    float4 av[4] = {a0, a1, a2, a3};
#pragma unroll
    for (int j = 0; j < 4; ++j) {
        int node = node0 + j;
        float4 a = av[j];
        float vs = dot4(a, sA);
        float vd = dot4(a, dA);
        vs += __shfl_xor(vs, 1, 64);
        vd += __shfl_xor(vd, 1, 64);
        if (node < n) {
            ushort4 q;
            q.x = f2bu(a.x); q.y = f2bu(a.y); q.z = f2bu(a.z); q.w = f2bu(a.w);
            *(ushort4*)(h1b + (long)node * H8 + cg * 4) = q;
            if ((lane & 1) == 0) {
                as1[node * 8 + (cg >> 1)] = vs;
                ad1[node * 8 + (cg >> 1)] = vd;
            }
        }
    }
}

// ---------------- Layer 1 aggregation + bias + ReLU ----------------
// wave per node. Compute role: lane = slot(8) x head(8) computes p for 16
// edges/round with no redundancy (exp without max-subtraction; |e| <~ 6 so
// fp32 exp is exact enough). Output role: lane = head(8) x chan(8)
// accumulates num via bpermute'd p. den = slot-butterfly.

__global__ __launch_bounds__(256) void k_agg1(const int* __restrict__ rp,
        const int* __restrict__ col, const ushort_t* __restrict__ h1b,
        const float* __restrict__ as1, const float* __restrict__ ad1,
        const float* __restrict__ b1, float* __restrict__ z1, int n) {
    int i = (blockIdx.x * 256 + threadIdx.x) >> 6;
    int lane = threadIdx.x & 63;
    if (i >= n) return;
    int slot = lane >> 3;   // compute: edge sub-index; ALSO output head hh
    int h2 = lane & 7;      // compute: head
    int beg = rp[i], end = rp[i + 1];
    int last = end - 1;
    int deg = end - beg;
    float adi = ad1[i * 8 + h2];
    float denp = 0.f, num = 0.f;
    const ushort_t* hb = h1b + lane;
    int rounds = (deg + 15) >> 4;
    for (int r = 0; r < rounds; ++r) {
        int kb = beg + r * 16;
        int kA = kb + slot, kB = kb + 8 + slot;
        int sA = col[min(kA, last)];
        int sB = col[min(kB, last)];
        int s[16];
#pragma unroll
        for (int j = 0; j < 16; ++j) s[j] = col[min(kb + j, last)];
        ushort_t u[16];
#pragma unroll
        for (int j = 0; j < 16; ++j) u[j] = hb[(long)s[j] * H8];
        float svA = as1[sA * 8 + h2];
        float svB = as1[sB * 8 + h2];
        float eA = svA + adi;
        eA = fmaxf(eA, 0.f) + 0.2f * fminf(eA, 0.f);
        float pA = (kA < end) ? __expf(eA) : 0.f;
        float eB = svB + adi;
        eB = fmaxf(eB, 0.f) + 0.2f * fminf(eB, 0.f);
        float pB = (kB < end) ? __expf(eB) : 0.f;
        denp += pA + pB;
#pragma unroll
        for (int j = 0; j < 8; ++j) {
            float pj = __shfl(pA, j * 8 + slot, 64);   // p[edge kb+j][head=slot]
            num += pj * bu2f(u[j]);
        }
#pragma unroll
        for (int j = 0; j < 8; ++j) {
            float pj = __shfl(pB, j * 8 + slot, 64);   // p[edge kb+8+j][head=slot]
            num += pj * bu2f(u[8 + j]);
        }
    }
    denp += __shfl_xor(denp, 8, 64);
    denp += __shfl_xor(denp, 16, 64);
    denp += __shfl_xor(denp, 32, 64);
    float den = __shfl(denp, slot, 64);   // den for output head (=slot bits)
    float o = num / (den + 1e-16f) + b1[lane];
    z1[(long)i * H8 + lane] = fmaxf(o, 0.f);
}

// ---------------- Layer 2 GEMM + attention dots (bf16 h2 out) ----------------

__global__ __launch_bounds__(256) void k_gemm2(const float* __restrict__ z1,
        const float* __restrict__ W2, const float* __restrict__ attS,
        const float* __restrict__ attD, ushort_t* __restrict__ h2b,
        float* __restrict__ as2, float* __restrict__ ad2) {
    __shared__ float ws[H8 * NC];     // 4 KB
    __shared__ float zs[16][H8 + 1];  // padded
    int t = threadIdx.x;
    for (int j = t; j < H8 * NC; j += 256) ws[j] = W2[j];
    int n0 = blockIdx.x * 16;
    for (int j = t; j < 16 * H8; j += 256) {
        int r = j >> 6, k2 = j & 63;
        zs[r][k2] = z1[(long)(n0 + r) * H8 + k2];
    }
    __syncthreads();
    int c = t & 15, g = t >> 4;
    float acc = 0.f;
#pragma unroll 8
    for (int k = 0; k < H8; ++k) acc += zs[g][k] * ws[k * NC + c];
    h2b[(long)(n0 + g) * NC + c] = f2bu(acc);
    float vs = acc * attS[c], vd = acc * attD[c];
    for (int off = 1; off < 16; off <<= 1) {
        vs += __shfl_xor(vs, off, 64);
        vd += __shfl_xor(vd, off, 64);
    }
    if (c == 0) { as2[n0 + g] = vs; ad2[n0 + g] = vd; }
}

// ---------------- Layer 2 aggregation + bias + log_softmax ----------------

__global__ __launch_bounds__(256) void k_agg2(const int* __restrict__ rp,
        const int* __restrict__ col, const ushort_t* __restrict__ h2b,
        const float* __restrict__ as2, const float* __restrict__ ad2,
        const float* __restrict__ b2, float* __restrict__ out, int n) {
    int i = (blockIdx.x * 256 + threadIdx.x) >> 6;
    int lane = threadIdx.x & 63;
    if (i >= n) return;
    int slot = lane >> 4, c = lane & 15;
    int beg = rp[i], end = rp[i + 1];
    int last = end - 1;
    int deg = end - beg;
    float adi = ad2[i];
    float den = 0.f, num = 0.f;
    int rounds = (deg + 7) >> 3;
    for (int r = 0; r < rounds; ++r) {
        int kb = beg + r * 8;
        int k0 = kb + slot, k1 = kb + 4 + slot;
        int s0 = col[min(k0, last)];
        int s1 = col[min(k1, last)];
        float sv0 = as2[s0], sv1 = as2[s1];
        ushort_t u0 = h2b[(long)s0 * NC + c];
        ushort_t u1 = h2b[(long)s1 * NC + c];
        float e0 = sv0 + adi;
        e0 = fmaxf(e0, 0.f) + 0.2f * fminf(e0, 0.f);
        float p0 = (k0 < end) ? __expf(e0) : 0.f;
        float e1 = sv1 + adi;
        e1 = fmaxf(e1, 0.f) + 0.2f * fminf(e1, 0.f);
        float p1 = (k1 < end) ? __expf(e1) : 0.f;
        den += p0 + p1;
        num += p0 * bu2f(u0) + p1 * bu2f(u1);
    }
    den += __shfl_xor(den, 16, 64);
    den += __shfl_xor(den, 32, 64);
    num += __shfl_xor(num, 16, 64);
    num += __shfl_xor(num, 32, 64);
    float o = num / (den + 1e-16f) + b2[c];
    float mx = o;
    for (int off = 1; off < 16; off <<= 1) mx = fmaxf(mx, __shfl_xor(mx, off, 64));
    float ev = __expf(o - mx);
    float sm = ev;
    for (int off = 1; off < 16; off <<= 1) sm += __shfl_xor(sm, off, 64);
    float res = o - mx - __logf(sm);
    if (slot == 0) out[(long)i * NC + c] = res;
}

// ---------------- launcher ----------------

extern "C" void kernel_launch(void* const* d_in, const int* in_sizes, int n_in,
                              void* d_out, int out_size, void* d_ws, size_t ws_size,
                              hipStream_t stream) {
    const float* x     = (const float*)d_in[0];
    const int*   ei    = (const int*)d_in[1];
    const float* W1    = (const float*)d_in[2];
    const float* attS1 = (const float*)d_in[3];
    const float* attD1 = (const float*)d_in[4];
    const float* b1    = (const float*)d_in[5];
    const float* W2    = (const float*)d_in[6];
    const float* attS2 = (const float*)d_in[7];
    const float* attD2 = (const float*)d_in[8];
    const float* b2    = (const float*)d_in[9];
    float* out = (float*)d_out;

    const int N = NN;
    const int E = in_sizes[1] / 2;
    const int NB = (N + (1 << BKS) - 1) >> BKS;
    const int NBLK = (E + CHUNK - 1) / CHUNK;

    float* fws = (float*)d_ws;
    float* z1  = fws;                       // N*64  (aliased by binned before agg1)
    float* as1 = z1 + (size_t)N * H8;       // N*8
    float* ad1 = as1 + (size_t)N * 8;       // N*8
    float* as2 = ad1 + (size_t)N * 8;       // N
    float* ad2 = as2 + N;                   // N
    ushort_t* h1b = (ushort_t*)(ad2 + N);   // N*64 bf16
    ushort_t* h2b = h1b + (size_t)N * H8;   // N*16 bf16
    int* deg  = (int*)(h2b + (size_t)N * NC);
    int* rp   = deg + N;                    // N+1
    int* wo   = rp + (N + 1);               // N
    int* col  = wo + N;                     // E+N
    int* bh   = col + (E + N);              // NBLK*NB
    int* bsum = bh + (size_t)NBLK * NB;     // <=256
    u64_t* binned = (u64_t*)z1;             // E * 8B

    const int* srcp = ei;
    const int* dstp = ei + E;

    int nb1024 = (N + 1023) / 1024;

    hipMemsetAsync(deg, 0, (size_t)N * 4, stream);
    k_binA<<<NBLK, 256, 0, stream>>>(dstp, bh, E, NB);
    k_binscan<<<1, 256, 0, stream>>>(bh, NBLK, NB);
    k_binC<<<NBLK, 256, 0, stream>>>(srcp, dstp, bh, binned, E, NB);
    k_count2<<<(E + 255) / 256, 256, 0, stream>>>(binned, deg, E);
    k_scan1<<<nb1024, 256, 0, stream>>>(deg, rp, bsum, N);
    k_scan2<<<1, 256, 0, stream>>>(bsum, nb1024);
    k_scan3<<<(N + 255) / 256, 256, 0, stream>>>(rp, bsum, N, E + N);
    k_selfloop<<<(N + 255) / 256, 256, 0, stream>>>(rp, wo, col, N);
    k_binD<<<(E + 255) / 256, 256, 0, stream>>>(binned, wo, col, E);

    k_gemm1<<<(N + 63) / 64, 256, 0, stream>>>(x, W1, attS1, attD1, h1b, as1, ad1, N);
    k_agg1<<<(N + 3) / 4, 256, 0, stream>>>(rp, col, h1b, as1, ad1, b1, z1, N);
    k_gemm2<<<N / 16, 256, 0, stream>>>(z1, W2, attS2, attD2, h2b, as2, ad2);
    k_agg2<<<(N + 3) / 4, 256, 0, stream>>>(rp, col, h2b, as2, ad2, b2, out, N);
}

// Round 5
// 242.792 us; speedup vs baseline: 2.1365x; 1.3575x over previous
//
#include <hip/hip_runtime.h>
#include <hip/hip_bf16.h>

#define NN 100000
#define FIN 128
#define H8 64      // heads*hid = 8*8
#define NC 16
#define BKS 9      // bucket shift: 512 nodes/bucket
#define CHUNK 8192 // edges per binning block

typedef unsigned short ushort_t;
typedef unsigned long long u64_t;

__device__ __forceinline__ float bu2f(ushort_t u) {
    unsigned v = ((unsigned)u) << 16;
    return __uint_as_float(v);
}
__device__ __forceinline__ ushort_t f2bu(float f) {
    __hip_bfloat16 h = __float2bfloat16(f);
    return *reinterpret_cast<ushort_t*>(&h);
}
__device__ __forceinline__ float dot4(float4 a, float4 b) {
    return a.x * b.x + a.y * b.y + a.z * b.z + a.w * b.w;
}
__device__ __forceinline__ void fma4(float4& a, float s, float4 w) {
    a.x += s * w.x; a.y += s * w.y; a.z += s * w.z; a.w += s * w.w;
}

// ---------------- binned CSR build ----------------

__global__ __launch_bounds__(256) void k_binA(const int* __restrict__ dst,
        int* __restrict__ bh, int e, int nb) {
    __shared__ int hist[256];
    int t = threadIdx.x;
    hist[t] = 0;
    __syncthreads();
    int base = blockIdx.x * CHUNK;
    int endj = min(base + CHUNK, e);
    for (int k0 = base + t * 4; k0 < endj; k0 += 1024) {
        if (k0 + 3 < endj) {
            int4 d4 = *(const int4*)(dst + k0);
            atomicAdd(&hist[d4.x >> BKS], 1);
            atomicAdd(&hist[d4.y >> BKS], 1);
            atomicAdd(&hist[d4.z >> BKS], 1);
            atomicAdd(&hist[d4.w >> BKS], 1);
        } else {
            for (int k = k0; k < endj; ++k) atomicAdd(&hist[dst[k] >> BKS], 1);
        }
    }
    __syncthreads();
    if (t < nb) bh[blockIdx.x * nb + t] = hist[t];
}

__global__ __launch_bounds__(256) void k_binscan(int* __restrict__ bh,
        int nblk, int nb) {
    __shared__ int ts[256];
    int j = threadIdx.x;
    int tot = 0;
    if (j < nb) {
#pragma unroll 8
        for (int b = 0; b < nblk; ++b) {
            int v = bh[b * nb + j];
            bh[b * nb + j] = tot;
            tot += v;
        }
    }
    ts[j] = tot;
    __syncthreads();
    int run = ts[j];
    for (int off = 1; off < 256; off <<= 1) {
        int y = (j >= off) ? ts[j - off] : 0;
        __syncthreads();
        run += y;
        ts[j] = run;
        __syncthreads();
    }
    int start = run - tot;   // exclusive over buckets
    if (j < nb) {
#pragma unroll 8
        for (int b = 0; b < nblk; ++b) bh[b * nb + j] += start;
    }
}

__global__ __launch_bounds__(256) void k_binC(const int* __restrict__ src,
        const int* __restrict__ dst, const int* __restrict__ bh,
        u64_t* __restrict__ binned, int e, int nb) {
    __shared__ int off[256];
    int t = threadIdx.x;
    if (t < nb) off[t] = bh[blockIdx.x * nb + t];
    __syncthreads();
    int base = blockIdx.x * CHUNK;
    int endj = min(base + CHUNK, e);
    for (int k0 = base + t * 4; k0 < endj; k0 += 1024) {
        if (k0 + 3 < endj) {
            int4 d4 = *(const int4*)(dst + k0);
            int4 s4 = *(const int4*)(src + k0);
            int p0 = atomicAdd(&off[d4.x >> BKS], 1);
            binned[p0] = ((u64_t)(unsigned)d4.x << 32) | (unsigned)s4.x;
            int p1 = atomicAdd(&off[d4.y >> BKS], 1);
            binned[p1] = ((u64_t)(unsigned)d4.y << 32) | (unsigned)s4.y;
            int p2 = atomicAdd(&off[d4.z >> BKS], 1);
            binned[p2] = ((u64_t)(unsigned)d4.z << 32) | (unsigned)s4.z;
            int p3 = atomicAdd(&off[d4.w >> BKS], 1);
            binned[p3] = ((u64_t)(unsigned)d4.w << 32) | (unsigned)s4.w;
        } else {
            for (int k = k0; k < endj; ++k) {
                int d = dst[k], s = src[k];
                int p = atomicAdd(&off[d >> BKS], 1);
                binned[p] = ((u64_t)(unsigned)d << 32) | (unsigned)s;
            }
        }
    }
}

// Fused per-bucket CSR finalize: degree hist + scan + selfloop + scatter.
// One block per bucket; bucket b covers nodes [b*512, b*512+512).
__global__ __launch_bounds__(256) void k_bucket(const u64_t* __restrict__ binned,
        const int* __restrict__ bstart, int* __restrict__ rp, int* __restrict__ col,
        int e, int n, int nb) {
    __shared__ int deg[512];
    __shared__ int ts[256];
    int b = blockIdx.x, t = threadIdx.x;
    int node0 = b << BKS;
    int S = bstart[b];
    int Se = (b + 1 < nb) ? bstart[b + 1] : e;
    deg[t] = 0; deg[t + 256] = 0;
    __syncthreads();
    for (int k = S + t; k < Se; k += 256)
        atomicAdd(&deg[(int)(binned[k] >> 32) - node0], 1);
    __syncthreads();
    int g0 = node0 + 2 * t, g1 = g0 + 1;
    int c0 = (g0 < n) ? deg[2 * t] + 1 : 0;      // +1 = self-loop
    int c1 = (g1 < n) ? deg[2 * t + 1] + 1 : 0;
    int s = c0 + c1;
    ts[t] = s;
    __syncthreads();
    int run = s;
    for (int off = 1; off < 256; off <<= 1) {
        int y = (t >= off) ? ts[t - off] : 0;
        __syncthreads();
        run += y;
        ts[t] = run;
        __syncthreads();
    }
    int ex = run - s;
    int base = S + node0;      // edges before bucket + selfloops before bucket
    int p0 = base + ex, p1 = base + ex + c0;
    if (g0 < n) { rp[g0] = p0; col[p0] = g0; deg[2 * t] = p0 + 1; }
    if (g1 < n) { rp[g1] = p1; col[p1] = g1; deg[2 * t + 1] = p1 + 1; }
    if (b == nb - 1 && t == 0) rp[n] = e + n;
    __syncthreads();
    for (int k = S + t; k < Se; k += 256) {
        u64_t pk = binned[k];
        int d = (int)(pk >> 32);
        int sv = (int)(pk & 0xffffffffu);
        int p = atomicAdd(&deg[d - node0], 1);
        col[p] = sv;
    }
}

// ---------------- Layer 1: h1 = x @ W1 (bf16 out) + fused att dots ----------------

__global__ __launch_bounds__(256) void k_gemm1(const float* __restrict__ x,
        const float* __restrict__ W, const float* __restrict__ attS,
        const float* __restrict__ attD, ushort_t* __restrict__ h1b,
        float* __restrict__ as1, float* __restrict__ ad1, int n) {
    __shared__ float ws[FIN * H8];    // 32 KB
    int t = threadIdx.x;
    const float4* W4 = (const float4*)W;
    float4* ws4 = (float4*)ws;
    for (int j = t; j < FIN * H8 / 4; j += 256) ws4[j] = W4[j];
    __syncthreads();

    int wv = t >> 6, lane = t & 63;
    int ng = lane >> 4, cg = lane & 15;
    int node0 = (blockIdx.x * 4 + wv) * 16 + ng * 4;

    int r0 = min(node0 + 0, n - 1), r1 = min(node0 + 1, n - 1);
    int r2 = min(node0 + 2, n - 1), r3 = min(node0 + 3, n - 1);
    const float* xp0 = x + (long)r0 * FIN;
    const float* xp1 = x + (long)r1 * FIN;
    const float* xp2 = x + (long)r2 * FIN;
    const float* xp3 = x + (long)r3 * FIN;

    float4 a0 = {0, 0, 0, 0}, a1 = {0, 0, 0, 0}, a2 = {0, 0, 0, 0}, a3 = {0, 0, 0, 0};
#pragma unroll 2
    for (int k = 0; k < FIN; k += 4) {
        float4 xa = *(const float4*)(xp0 + k);
        float4 xb = *(const float4*)(xp1 + k);
        float4 xc = *(const float4*)(xp2 + k);
        float4 xd = *(const float4*)(xp3 + k);
        float4 w0 = *(const float4*)(ws + (k + 0) * H8 + cg * 4);
        float4 w1 = *(const float4*)(ws + (k + 1) * H8 + cg * 4);
        float4 w2 = *(const float4*)(ws + (k + 2) * H8 + cg * 4);
        float4 w3 = *(const float4*)(ws + (k + 3) * H8 + cg * 4);
        fma4(a0, xa.x, w0); fma4(a0, xa.y, w1); fma4(a0, xa.z, w2); fma4(a0, xa.w, w3);
        fma4(a1, xb.x, w0); fma4(a1, xb.y, w1); fma4(a1, xb.z, w2); fma4(a1, xb.w, w3);
        fma4(a2, xc.x, w0); fma4(a2, xc.y, w1); fma4(a2, xc.z, w2); fma4(a2, xc.w, w3);
        fma4(a3, xd.x, w0); fma4(a3, xd.y, w1); fma4(a3, xd.z, w2); fma4(a3, xd.w, w3);
    }

    float4 sA = *(const float4*)(attS + cg * 4);
    float4 dA = *(const float4*)(attD + cg * 4);
    float4 av[4] = {a0, a1, a2, a3};
#pragma unroll
    for (int j = 0; j < 4; ++j) {
        int node = node0 + j;
        float4 a = av[j];
        float vs = dot4(a, sA);
        float vd = dot4(a, dA);
        vs += __shfl_xor(vs, 1, 64);
        vd += __shfl_xor(vd, 1, 64);
        if (node < n) {
            ushort4 q;
            q.x = f2bu(a.x); q.y = f2bu(a.y); q.z = f2bu(a.z); q.w = f2bu(a.w);
            *(ushort4*)(h1b + (long)node * H8 + cg * 4) = q;
            if ((lane & 1) == 0) {
                as1[node * 8 + (cg >> 1)] = vs;
                ad1[node * 8 + (cg >> 1)] = vd;
            }
        }
    }
}

// ---------------- Layer 1 aggregation + bias + ReLU ----------------
// wave per node. col is wave-uniform -> readlane to SGPR, scalar-base gathers.
// Compute role: lane = slot(8) x head(8) computes p for 16 edges/round.
// Output role: lane = head(8)=slot x chan(8)=h2 accumulates num via bpermute'd p.

__global__ __launch_bounds__(256) void k_agg1(const int* __restrict__ rp,
        const int* __restrict__ col, const ushort_t* __restrict__ h1b,
        const float* __restrict__ as1, const float* __restrict__ ad1,
        const float* __restrict__ b1, float* __restrict__ z1, int n) {
    int i = (blockIdx.x * 256 + threadIdx.x) >> 6;
    int lane = threadIdx.x & 63;
    if (i >= n) return;
    int slot = lane >> 3;   // compute: edge sub-index; ALSO output head
    int h2 = lane & 7;      // compute: head
    int beg = rp[i], end = rp[i + 1];
    int last = end - 1;
    int deg = end - beg;
    float adi = ad1[i * 8 + h2];
    float denp = 0.f, num = 0.f;
    int rounds = (deg + 15) >> 4;
    for (int r = 0; r < rounds; ++r) {
        int k = beg + r * 16;
        int v = col[min(k + (lane & 15), last)];
        int kA = k + slot, kB = kA + 8;
        int sA = __shfl(v, slot, 64);        // col[k+slot]
        int sB = __shfl(v, 8 + slot, 64);    // col[k+8+slot]
        float svA = as1[sA * 8 + h2];
        float svB = as1[sB * 8 + h2];
        float eA = svA + adi;
        eA = fmaxf(eA, 0.f) + 0.2f * fminf(eA, 0.f);
        float pA = (kA < end) ? __expf(eA) : 0.f;
        float eB = svB + adi;
        eB = fmaxf(eB, 0.f) + 0.2f * fminf(eB, 0.f);
        float pB = (kB < end) ? __expf(eB) : 0.f;
        denp += pA + pB;
        float uf[16];
#pragma unroll
        for (int j = 0; j < 16; ++j) {
            int sj = __builtin_amdgcn_readlane(v, j);          // SGPR
            const ushort_t* rowp = h1b + ((size_t)(unsigned)sj << 6);
            uf[j] = bu2f(rowp[lane]);                          // scalar base + lane off
        }
#pragma unroll
        for (int j = 0; j < 8; ++j) {
            float pj = __shfl(pA, j * 8 + slot, 64);   // p[edge k+j][head=slot]
            num += pj * uf[j];
        }
#pragma unroll
        for (int j = 0; j < 8; ++j) {
            float pj = __shfl(pB, j * 8 + slot, 64);   // p[edge k+8+j][head=slot]
            num += pj * uf[8 + j];
        }
    }
    denp += __shfl_xor(denp, 8, 64);
    denp += __shfl_xor(denp, 16, 64);
    denp += __shfl_xor(denp, 32, 64);
    float den = __shfl(denp, slot, 64);   // den for output head (=slot)
    float o = num / (den + 1e-16f) + b1[lane];
    z1[(long)i * H8 + lane] = fmaxf(o, 0.f);
}

// ---------------- Layer 2 GEMM + attention dots (bf16 h2 out) ----------------

__global__ __launch_bounds__(256) void k_gemm2(const float* __restrict__ z1,
        const float* __restrict__ W2, const float* __restrict__ attS,
        const float* __restrict__ attD, ushort_t* __restrict__ h2b,
        float* __restrict__ as2, float* __restrict__ ad2) {
    __shared__ float ws[H8 * NC];     // 4 KB
    __shared__ float zs[16][H8 + 1];  // padded
    int t = threadIdx.x;
    for (int j = t; j < H8 * NC; j += 256) ws[j] = W2[j];
    int n0 = blockIdx.x * 16;
    for (int j = t; j < 16 * H8; j += 256) {
        int r = j >> 6, k2 = j & 63;
        zs[r][k2] = z1[(long)(n0 + r) * H8 + k2];
    }
    __syncthreads();
    int c = t & 15, g = t >> 4;
    float acc = 0.f;
#pragma unroll 8
    for (int k = 0; k < H8; ++k) acc += zs[g][k] * ws[k * NC + c];
    h2b[(long)(n0 + g) * NC + c] = f2bu(acc);
    float vs = acc * attS[c], vd = acc * attD[c];
    for (int off = 1; off < 16; off <<= 1) {
        vs += __shfl_xor(vs, off, 64);
        vd += __shfl_xor(vd, off, 64);
    }
    if (c == 0) { as2[n0 + g] = vs; ad2[n0 + g] = vd; }
}

// ---------------- Layer 2 aggregation + bias + log_softmax ----------------
// wave per node; lane c = lane&15. All lanes process all 16 edges/round via
// scalar (readlane) p and source index -> no slot merge needed for num.

__global__ __launch_bounds__(256) void k_agg2(const int* __restrict__ rp,
        const int* __restrict__ col, const ushort_t* __restrict__ h2b,
        const float* __restrict__ as2, const float* __restrict__ ad2,
        const float* __restrict__ b2, float* __restrict__ out, int n) {
    int i = (blockIdx.x * 256 + threadIdx.x) >> 6;
    int lane = threadIdx.x & 63;
    if (i >= n) return;
    int c = lane & 15;
    int beg = rp[i], end = rp[i + 1];
    int last = end - 1;
    int deg = end - beg;
    float adi = ad2[i];
    float denp = 0.f, num = 0.f;
    int rounds = (deg + 15) >> 4;
    for (int r = 0; r < rounds; ++r) {
        int k = beg + r * 16;
        int ki = k + c;
        int v = col[min(ki, last)];
        float sv = as2[v];
        float e = sv + adi;
        e = fmaxf(e, 0.f) + 0.2f * fminf(e, 0.f);
        float p = (ki < end) ? __expf(e) : 0.f;
        denp += p;
#pragma unroll
        for (int j = 0; j < 16; ++j) {
            int sj = __builtin_amdgcn_readlane(v, j);                       // SGPR
            float pj = __uint_as_float(
                __builtin_amdgcn_readlane(__float_as_uint(p), j));          // SGPR
            const ushort_t* rowp = h2b + ((size_t)(unsigned)sj << 4);
            num += pj * bu2f(rowp[c]);
        }
    }
    denp += __shfl_xor(denp, 1, 64);
    denp += __shfl_xor(denp, 2, 64);
    denp += __shfl_xor(denp, 4, 64);
    denp += __shfl_xor(denp, 8, 64);
    float o = num / (denp + 1e-16f) + b2[c];
    float mx = o;
    for (int off = 1; off < 16; off <<= 1) mx = fmaxf(mx, __shfl_xor(mx, off, 64));
    float ev = __expf(o - mx);
    float sm = ev;
    for (int off = 1; off < 16; off <<= 1) sm += __shfl_xor(sm, off, 64);
    float res = o - mx - __logf(sm);
    if (lane < 16) out[(long)i * NC + c] = res;
}

// ---------------- launcher ----------------

extern "C" void kernel_launch(void* const* d_in, const int* in_sizes, int n_in,
                              void* d_out, int out_size, void* d_ws, size_t ws_size,
                              hipStream_t stream) {
    const float* x     = (const float*)d_in[0];
    const int*   ei    = (const int*)d_in[1];
    const float* W1    = (const float*)d_in[2];
    const float* attS1 = (const float*)d_in[3];
    const float* attD1 = (const float*)d_in[4];
    const float* b1    = (const float*)d_in[5];
    const float* W2    = (const float*)d_in[6];
    const float* attS2 = (const float*)d_in[7];
    const float* attD2 = (const float*)d_in[8];
    const float* b2    = (const float*)d_in[9];
    float* out = (float*)d_out;

    const int N = NN;
    const int E = in_sizes[1] / 2;
    const int NB = (N + (1 << BKS) - 1) >> BKS;      // buckets
    const int NBLK = (E + CHUNK - 1) / CHUNK;        // binning blocks

    float* fws = (float*)d_ws;
    float* z1  = fws;                       // N*64  (aliased by binned before agg1)
    float* as1 = z1 + (size_t)N * H8;       // N*8
    float* ad1 = as1 + (size_t)N * 8;       // N*8
    float* as2 = ad1 + (size_t)N * 8;       // N
    float* ad2 = as2 + N;                   // N
    ushort_t* h1b = (ushort_t*)(ad2 + N);   // N*64 bf16
    ushort_t* h2b = h1b + (size_t)N * H8;   // N*16 bf16
    int* rp   = (int*)(h2b + (size_t)N * NC);  // N+1
    int* col  = rp + (N + 1);               // E+N
    int* bh   = col + (E + N);              // NBLK*NB
    u64_t* binned = (u64_t*)z1;             // E * 8B  (z1 is 25.6MB >= 12.8MB)

    const int* srcp = ei;
    const int* dstp = ei + E;

    k_binA<<<NBLK, 256, 0, stream>>>(dstp, bh, E, NB);
    k_binscan<<<1, 256, 0, stream>>>(bh, NBLK, NB);
    k_binC<<<NBLK, 256, 0, stream>>>(srcp, dstp, bh, binned, E, NB);
    k_bucket<<<NB, 256, 0, stream>>>(binned, bh, rp, col, E, N, NB);

    k_gemm1<<<(N + 63) / 64, 256, 0, stream>>>(x, W1, attS1, attD1, h1b, as1, ad1, N);
    k_agg1<<<(N + 3) / 4, 256, 0, stream>>>(rp, col, h1b, as1, ad1, b1, z1, N);
    k_gemm2<<<N / 16, 256, 0, stream>>>(z1, W2, attS2, attD2, h2b, as2, ad2);
    k_agg2<<<(N + 3) / 4, 256, 0, stream>>>(rp, col, h2b, as2, ad2, b2, out, N);
}